// Round 14
// baseline (84.919 us; speedup 1.0000x reference)
//
#include <hip/hip_runtime.h>
#include <hip/hip_bf16.h>
#include <math.h>

constexpr int Bb = 2, Hh = 16, Tt = 2048;

typedef __attribute__((ext_vector_type(8))) _Float16 f16x8;
typedef __attribute__((ext_vector_type(8))) short bf16x8;
typedef __attribute__((ext_vector_type(4))) float f32x4;
typedef __attribute__((ext_vector_type(16))) float f32x16;
typedef __attribute__((ext_vector_type(4))) unsigned int u32x4;
typedef unsigned int u32;

__device__ __forceinline__ short f2bf(float x){ __hip_bfloat16 h = __float2bfloat16(x); return *(short*)&h; }
// 64-elem-row swizzle helpers (prep_v's internal transpose)
__device__ __forceinline__ int swze(int row, int e){ return row*64 + ((((e>>3) ^ (row&7))<<3) | (e&7)); }
__device__ __forceinline__ int swzg(int row, int e0){ return row*64 + ((((e0>>3) ^ (row&7))<<3)); }

__device__ __forceinline__ void gll16(const void* g, void* l){
  __builtin_amdgcn_global_load_lds((const __attribute__((address_space(1))) u32*)g,
                                   (__attribute__((address_space(3))) u32*)l, 16, 0, 0);
}
__device__ __forceinline__ u32 cvtpk(float lo, float hi){
  u32 d; asm("v_cvt_pk_bf16_f32 %0, %1, %2" : "=v"(d) : "v"(lo), "v"(hi)); return d;
}

// ---------- prep 1: E fp32 -> f16 hi/lo 64x64 tile images, XOR-swizzled (LDS byte-exact) ----------
__global__ __launch_bounds__(256) void prep_e(const float* __restrict__ E, char* __restrict__ Eimg){
  const float* src = E + (size_t)blockIdx.x * 4096;
  char* dst = Eimg + (size_t)blockIdx.x * 16384;
#pragma unroll
  for (int i = 0; i < 2; ++i) {
    const int gid = threadIdx.x + 256 * i;
    const int row = gid >> 3, gc = gid & 7;
    const float* s8 = src + row * 64 + gc * 8;
    float4 a = *(const float4*)s8;
    float4 c = *(const float4*)(s8 + 4);
    float v[8] = {a.x, a.y, a.z, a.w, c.x, c.y, c.z, c.w};
    f16x8 hv, lv;
#pragma unroll
    for (int k = 0; k < 8; ++k) {
      _Float16 hi = (_Float16)v[k];
      hv[k] = hi; lv[k] = (_Float16)(v[k] - (float)hi);
    }
    const int off = row * 128 + ((gc ^ (row & 7)) << 4);
    *(f16x8*)(dst + off) = hv;
    *(f16x8*)(dst + 8192 + off) = lv;
  }
}

// ---------- prep 2: V fp32 [bh][s][d] -> bf16 transposed GRANULE-MAJOR tiles: [g8][d] 16B granules ----------
__global__ __launch_bounds__(256) void prep_v(const float* __restrict__ V, char* __restrict__ Vimg){
  __shared__ __align__(16) short Tl[64 * 64];
  const int tid = threadIdx.x;
  const int j = blockIdx.x & 31, bh = blockIdx.x >> 5;
  const int s0 = j * 64;
  {
    const int r = tid >> 2, c0 = (tid & 3) * 16;
    const float* src = V + ((size_t)bh * Tt + s0 + r) * 64 + c0;
#pragma unroll
    for (int i = 0; i < 4; ++i) {
      float4 t4 = ((const float4*)src)[i];
      float vv[4] = {t4.x, t4.y, t4.z, t4.w};
#pragma unroll
      for (int k = 0; k < 4; ++k) Tl[swze(c0 + 4 * i + k, r)] = f2bf(vv[k]);
    }
  }
  __syncthreads();
  {
    const int d = tid >> 2, sg = (tid & 3) * 16;
    bf16x8 a = *(const bf16x8*)&Tl[swzg(d, sg)];
    bf16x8 b = *(const bf16x8*)&Tl[swzg(d, sg + 8)];
    char* dst = Vimg + (size_t)blockIdx.x * 8192;
    *(bf16x8*)(dst + (sg >> 3) * 1024 + d * 16)       = a;
    *(bf16x8*)(dst + ((sg >> 3) + 1) * 1024 + d * 16) = b;
  }
}

// ---------- main: round-9 pipeline, NO setprio (compiler may interleave LIF into MFMA chain),
// ---------- lsum via MFMA-with-ones (oaccL), simplified epilogue ----------
__global__ __launch_bounds__(256, 3) void lif_attn14(
    const float* __restrict__ Q, const float* __restrict__ gain, const float* __restrict__ bias,
    const char* __restrict__ Eimg, const char* __restrict__ Vimg, float* __restrict__ out)
{
  __shared__ __align__(16) char Eb[2][16384];   // E tile hi+lo, double-buffered (reused as red[] in epilogue)

  const int tid = threadIdx.x, lane = tid & 63;
  const int l31 = lane & 31, hi2 = lane >> 5;
  const int w = tid >> 6, wc = w & 1, wr = w >> 1;  // wc = t-half; wr = s-half
  const int bh = blockIdx.x & 31, tb = 31 - (blockIdx.x >> 5);  // big tiles dispatched first
  const int b = bh >> 4, h = bh & 15, t0 = tb * 64;
  const int tg = t0 + 32 * wc + l31;            // this lane's query row

  const char* etile = Eimg + (size_t)(h * 32) * 16384;
  const char* vtile = Vimg + (size_t)(bh * 32) * 8192;

  // ---- Q fragments f16 hi/lo (loop-invariant, B-operand: k = 16kk + 8hi2 + j) ----
  f16x8 qh[4], ql[4];
  {
    const float* qp = Q + ((size_t)(b * Hh + h) * Tt + tg) * 64 + 8 * hi2;
#pragma unroll
    for (int kk = 0; kk < 4; ++kk) {
      const float* p0 = qp + 16 * kk;
      float4 a = *(const float4*)p0;
      float4 c = *(const float4*)(p0 + 4);
      float v[8] = {a.x, a.y, a.z, a.w, c.x, c.y, c.z, c.w};
#pragma unroll
      for (int k = 0; k < 8; ++k) {
        _Float16 hi = (_Float16)v[k];
        qh[kk][k] = hi; ql[kk][k] = (_Float16)(v[k] - (float)hi);
      }
    }
  }
  const float gt = gain[h * Tt + tg], bt = bias[h * Tt + tg];

  // E LDS read base: row rS = 32wr + l31, granule 2kk + hi2 (kk via addr XOR kk<<5)
  const int rS = 32 * wr + l31;
  const int eB = rS * 128 + ((hi2 ^ (rS & 7)) << 4);

  // V global-load lane pointers (granule-major tiles; coalesced 16B/lane)
  const int g8a = 4 * wr + hi2;
  const char* vp0 = vtile + g8a * 1024 + l31 * 16;
  const char* vp1 = vtile + g8a * 1024 + (32 + l31) * 16;
  const char* vp2 = vtile + (g8a + 2) * 1024 + l31 * 16;
  const char* vp3 = vtile + (g8a + 2) * 1024 + (32 + l31) * 16;

  // ones vector (bf16 1.0) for the lsum MFMA
  bf16x8 onesv;
#pragma unroll
  for (int i = 0; i < 8; ++i) onesv[i] = (short)0x3F80;

  f32x16 oacc0 = 0.f, oacc1 = 0.f;   // partial O[t-half wc][d 0..31 / 32..63], this wave's s-half
  f32x16 oaccL = 0.f;                // row sums (same D layout; every column identical)
  f32x16 sA, sB;
  bf16x8 vA[4], vB[4];

  auto STAGE_E = [&](int n, int buf) {
    const char* g = etile + (size_t)n * 16384 + tid * 16;
    char* l = &Eb[buf][0] + tid * 16;
#pragma unroll
    for (int c2 = 0; c2 < 4; ++c2) gll16(g + c2 * 4096, l + c2 * 4096);
  };
  auto SSTEP = [&](int buf, f32x16& acc) {   // S^T = E·Q^T, split f16 (hh + lh + hl)
    const char* ec = &Eb[buf][0];
    acc = 0.f;
#pragma unroll
    for (int kk = 0; kk < 4; ++kk) {
      f16x8 eh = *(const f16x8*)(ec + (eB ^ (kk << 5)));
      f16x8 el = *(const f16x8*)(ec + 8192 + (eB ^ (kk << 5)));
      acc = __builtin_amdgcn_mfma_f32_32x32x16_f16(eh, qh[kk], acc, 0, 0, 0);
      acc = __builtin_amdgcn_mfma_f32_32x32x16_f16(el, qh[kk], acc, 0, 0, 0);
      acc = __builtin_amdgcn_mfma_f32_32x32x16_f16(eh, ql[kk], acc, 0, 0, 0);
    }
  };
  auto VLOAD = [&](int n, bf16x8* vv) {
    const size_t o = (size_t)n * 8192;
    vv[0] = *(const bf16x8*)(vp0 + o);
    vv[1] = *(const bf16x8*)(vp1 + o);
    vv[2] = *(const bf16x8*)(vp2 + o);
    vv[3] = *(const bf16x8*)(vp3 + o);
  };

  // BODY(j): stage E(j+2) [vm order pinned]; S(j+1) MFMA + LIF(j) VALU (freely interleavable);
  // PV(j) incl. lsum MFMA. Loop-end (outside): s_waitcnt vmcnt(4) + raw barrier.
  auto BODY = [&](int j, f32x16& cur, f32x16& nxt, bf16x8* vc, bf16x8* vn) {
    if (j + 2 <= tb) STAGE_E(j + 2, j & 1);
    __builtin_amdgcn_sched_barrier(0);        // pin vm issue order: E-stage before V-loads
    if (j + 1 <= tb) { SSTEP((j + 1) & 1, nxt); VLOAD(j + 1, vn); }
    // LIF + fixed-shift exp; branchless: arg<0 for non-firing I -> NaN chain -> fmaxf picks e^-62.5
    float p[16];
#pragma unroll
    for (int r = 0; r < 16; ++r) {
      const float I = fmaf(gt, cur[r], bt);
      const float a = (I - 1.0f) * __builtin_fabsf(__builtin_amdgcn_rcpf(I));
      const float L2 = __log2f(a);                                      // NaN unless I > 1
      const float den = fmaf(-0.013862944f, L2, 0.002f);                // tau_ref - tau_rc*ln((I-1)/I)
      const float rd = __builtin_amdgcn_rcpf(den);
      const float pv = __builtin_amdgcn_exp2f(fmaf(0.18033688f, rd, -90.169312f));  // exp(score-62.5)
      p[r] = fmaxf(pv, 7.1892351e-28f);                                 // non-firing: exp(0 - 62.5)
    }
    if (j == tb) {                      // causal mask: only the diagonal tile
#pragma unroll
      for (int rq = 0; rq < 4; ++rq)
#pragma unroll
        for (int rr = 0; rr < 4; ++rr)
          if (32 * wr + 8 * rq + 4 * hi2 + rr > 32 * wc + l31) p[4 * rq + rr] = 0.f;
    }
    // PV: pack P to bf16 A-frags in-register (cvt_pk + permlane32_swap); V from registers;
    // row-sum via MFMA against ones (replaces 16 v_add + epilogue shuffle).
#pragma unroll
    for (int kp = 0; kp < 2; ++kp) {
      u32 x0 = cvtpk(p[8 * kp + 0], p[8 * kp + 1]);
      u32 x1 = cvtpk(p[8 * kp + 2], p[8 * kp + 3]);
      u32 y0 = cvtpk(p[8 * kp + 4], p[8 * kp + 5]);
      u32 y1 = cvtpk(p[8 * kp + 6], p[8 * kp + 7]);
      asm("v_permlane32_swap_b32 %0, %1" : "+v"(x0), "+v"(y0));
      asm("v_permlane32_swap_b32 %0, %1" : "+v"(x1), "+v"(y1));
      u32x4 af = {x0, x1, y0, y1};      // lane holds P[t=l31][s_rel = 32wr + 16kp + 8hi2 + 0..7]
      bf16x8 pa = *(bf16x8*)&af;
      oacc0 = __builtin_amdgcn_mfma_f32_32x32x16_bf16(pa, vc[2 * kp + 0], oacc0, 0, 0, 0);
      oacc1 = __builtin_amdgcn_mfma_f32_32x32x16_bf16(pa, vc[2 * kp + 1], oacc1, 0, 0, 0);
      oaccL = __builtin_amdgcn_mfma_f32_32x32x16_bf16(pa, onesv, oaccL, 0, 0, 0);
    }
  };

  // ---- prologue: E(0),E(1),V(0); S(0) ----
  STAGE_E(0, 0);
  if (tb >= 1) STAGE_E(1, 1);
  __builtin_amdgcn_sched_barrier(0);
  VLOAD(0, vA);
  asm volatile("s_waitcnt vmcnt(4)" ::: "memory");   // E(0),E(1) resident; V(0) in flight
  __builtin_amdgcn_s_barrier();
  __builtin_amdgcn_sched_barrier(0);
  SSTEP(0, sA);
  asm volatile("s_waitcnt vmcnt(4)" ::: "memory");
  __builtin_amdgcn_s_barrier();                      // WAR: Eb[0] reads done before BODY(0) restages it
  __builtin_amdgcn_sched_barrier(0);

  int j = 0;
  for (;;) {
    BODY(j, sA, sB, vA, vB);
    if (j == tb) break;
    asm volatile("s_waitcnt vmcnt(4)" ::: "memory"); // E(j+2) resident; V(j+1) stays in flight
    __builtin_amdgcn_s_barrier();
    __builtin_amdgcn_sched_barrier(0);
    ++j;
    BODY(j, sB, sA, vB, vA);
    if (j == tb) break;
    asm volatile("s_waitcnt vmcnt(4)" ::: "memory");
    __builtin_amdgcn_s_barrier();
    __builtin_amdgcn_sched_barrier(0);
    ++j;
  }

  // ---- epilogue: cross-wave (wr) reduction of oacc0/oacc1/oaccL through LDS, once per block ----
  __syncthreads();                                    // all Eb reads done -> safe to reuse as red[]
  float* red  = (float*)&Eb[0][0];                    // [wc][t_in_half 0..31][d 0..63] f32 (16 KB)
  float* redL = (float*)&Eb[1][0];                    // [wc][t_in_half 0..31] f32 (256 B)
  if (wr == 1) {
#pragma unroll
    for (int rq = 0; rq < 4; ++rq)
#pragma unroll
      for (int rr = 0; rr < 4; ++rr) {
        const int tr = 8 * rq + 4 * hi2 + rr;
        red[wc * 2048 + tr * 64 + l31]      = oacc0[4 * rq + rr];
        red[wc * 2048 + tr * 64 + 32 + l31] = oacc1[4 * rq + rr];
      }
    if (l31 == 0) {                                   // cols identical; lane 0 / lane 32 cover hi2 rows
#pragma unroll
      for (int r = 0; r < 16; ++r) {
        const int tr = (r & 3) + 8 * (r >> 2) + 4 * hi2;
        redL[wc * 32 + tr] = oaccL[r];
      }
    }
  }
  __syncthreads();
  if (wr == 0) {
    float* ob = out + ((size_t)(b * Hh + h) * Tt + t0 + 32 * wc) * 64;
#pragma unroll
    for (int rq = 0; rq < 4; ++rq) {
#pragma unroll
      for (int rr = 0; rr < 4; ++rr) {
        const int tr = 8 * rq + 4 * hi2 + rr;
        const float linv = __builtin_amdgcn_rcpf(oaccL[4 * rq + rr] + redL[wc * 32 + tr]);
        const float o0 = oacc0[4 * rq + rr] + red[wc * 2048 + tr * 64 + l31];
        const float o1 = oacc1[4 * rq + rr] + red[wc * 2048 + tr * 64 + 32 + l31];
        ob[(size_t)tr * 64 + l31]      = o0 * linv;
        ob[(size_t)tr * 64 + 32 + l31] = o1 * linv;
      }
    }
  }
}

extern "C" void kernel_launch(void* const* d_in, const int* in_sizes, int n_in,
                              void* d_out, int out_size, void* d_ws, size_t ws_size,
                              hipStream_t stream) {
  const float* Q    = (const float*)d_in[0];
  // d_in[1] = K is UNUSED by the reference (scores use enc_hat)
  const float* V    = (const float*)d_in[2];
  const float* E    = (const float*)d_in[3];
  const float* gain = (const float*)d_in[4];
  const float* bias = (const float*)d_in[5];
  float* out = (float*)d_out;

  constexpr size_t EIMG_BYTES = (size_t)Hh * 32 * 16384;        // 8 MiB
  char* Eimg = (char*)d_ws;
  char* Vimg = (char*)d_ws + EIMG_BYTES;                        // 8 MiB

  prep_e<<<Hh * 32, 256, 0, stream>>>(E, Eimg);
  prep_v<<<Bb * Hh * 32, 256, 0, stream>>>(V, Vimg);
  lif_attn14<<<1024, 256, 0, stream>>>(Q, gain, bias, Eimg, Vimg, out);
}

// Round 15
// 72.141 us; speedup vs baseline: 1.1771x; 1.1771x over previous
//
#include <hip/hip_runtime.h>
#include <hip/hip_bf16.h>
#include <math.h>

constexpr int Bb = 2, Hh = 16, Tt = 2048;

typedef __attribute__((ext_vector_type(8))) _Float16 f16x8;
typedef __attribute__((ext_vector_type(8))) short bf16x8;
typedef __attribute__((ext_vector_type(4))) float f32x4;
typedef __attribute__((ext_vector_type(16))) float f32x16;
typedef __attribute__((ext_vector_type(4))) unsigned int u32x4;
typedef unsigned int u32;

__device__ __forceinline__ short f2bf(float x){ __hip_bfloat16 h = __float2bfloat16(x); return *(short*)&h; }
// 64-elem-row swizzle helpers (prep_v's internal transpose)
__device__ __forceinline__ int swze(int row, int e){ return row*64 + ((((e>>3) ^ (row&7))<<3) | (e&7)); }
__device__ __forceinline__ int swzg(int row, int e0){ return row*64 + ((((e0>>3) ^ (row&7))<<3)); }

__device__ __forceinline__ void gll16(const void* g, void* l){
  __builtin_amdgcn_global_load_lds((const __attribute__((address_space(1))) u32*)g,
                                   (__attribute__((address_space(3))) u32*)l, 16, 0, 0);
}
__device__ __forceinline__ u32 cvtpk(float lo, float hi){
  u32 d; asm("v_cvt_pk_bf16_f32 %0, %1, %2" : "=v"(d) : "v"(lo), "v"(hi)); return d;
}

// ---------- prep 1: E fp32 -> f16 hi/lo 64x64 tile images, XOR-swizzled (LDS byte-exact) ----------
__global__ __launch_bounds__(256) void prep_e(const float* __restrict__ E, char* __restrict__ Eimg){
  const float* src = E + (size_t)blockIdx.x * 4096;
  char* dst = Eimg + (size_t)blockIdx.x * 16384;
#pragma unroll
  for (int i = 0; i < 2; ++i) {
    const int gid = threadIdx.x + 256 * i;
    const int row = gid >> 3, gc = gid & 7;
    const float* s8 = src + row * 64 + gc * 8;
    float4 a = *(const float4*)s8;
    float4 c = *(const float4*)(s8 + 4);
    float v[8] = {a.x, a.y, a.z, a.w, c.x, c.y, c.z, c.w};
    f16x8 hv, lv;
#pragma unroll
    for (int k = 0; k < 8; ++k) {
      _Float16 hi = (_Float16)v[k];
      hv[k] = hi; lv[k] = (_Float16)(v[k] - (float)hi);
    }
    const int off = row * 128 + ((gc ^ (row & 7)) << 4);
    *(f16x8*)(dst + off) = hv;
    *(f16x8*)(dst + 8192 + off) = lv;
  }
}

// ---------- prep 2: V fp32 [bh][s][d] -> bf16 transposed GRANULE-MAJOR tiles: [g8][d] 16B granules ----------
__global__ __launch_bounds__(256) void prep_v(const float* __restrict__ V, char* __restrict__ Vimg){
  __shared__ __align__(16) short Tl[64 * 64];
  const int tid = threadIdx.x;
  const int j = blockIdx.x & 31, bh = blockIdx.x >> 5;
  const int s0 = j * 64;
  {
    const int r = tid >> 2, c0 = (tid & 3) * 16;
    const float* src = V + ((size_t)bh * Tt + s0 + r) * 64 + c0;
#pragma unroll
    for (int i = 0; i < 4; ++i) {
      float4 t4 = ((const float4*)src)[i];
      float vv[4] = {t4.x, t4.y, t4.z, t4.w};
#pragma unroll
      for (int k = 0; k < 4; ++k) Tl[swze(c0 + 4 * i + k, r)] = f2bf(vv[k]);
    }
  }
  __syncthreads();
  {
    const int d = tid >> 2, sg = (tid & 3) * 16;
    bf16x8 a = *(const bf16x8*)&Tl[swzg(d, sg)];
    bf16x8 b = *(const bf16x8*)&Tl[swzg(d, sg + 8)];
    char* dst = Vimg + (size_t)blockIdx.x * 8192;
    *(bf16x8*)(dst + (sg >> 3) * 1024 + d * 16)       = a;
    *(bf16x8*)(dst + ((sg >> 3) + 1) * 1024 + d * 16) = b;
  }
}

// ---------- main: round-9 pipeline with s_setprio REMOVED (single-variable test) ----------
__global__ __launch_bounds__(256, 3) void lif_attn15(
    const float* __restrict__ Q, const float* __restrict__ gain, const float* __restrict__ bias,
    const char* __restrict__ Eimg, const char* __restrict__ Vimg, float* __restrict__ out)
{
  __shared__ __align__(16) char Eb[2][16384];   // E tile hi+lo, double-buffered (reused as red[] in epilogue)
  __shared__ __align__(16) float LsS[128];      // lsum partials [wr][wc][t_in_half]

  const int tid = threadIdx.x, lane = tid & 63;
  const int l31 = lane & 31, hi2 = lane >> 5;
  const int w = tid >> 6, wc = w & 1, wr = w >> 1;  // wc = t-half; wr = s-half
  const int bh = blockIdx.x & 31, tb = 31 - (blockIdx.x >> 5);  // big tiles dispatched first
  const int b = bh >> 4, h = bh & 15, t0 = tb * 64;
  const int tg = t0 + 32 * wc + l31;            // this lane's query row

  const char* etile = Eimg + (size_t)(h * 32) * 16384;
  const char* vtile = Vimg + (size_t)(bh * 32) * 8192;

  // ---- Q fragments f16 hi/lo (loop-invariant, B-operand: k = 16kk + 8hi2 + j) ----
  f16x8 qh[4], ql[4];
  {
    const float* qp = Q + ((size_t)(b * Hh + h) * Tt + tg) * 64 + 8 * hi2;
#pragma unroll
    for (int kk = 0; kk < 4; ++kk) {
      const float* p0 = qp + 16 * kk;
      float4 a = *(const float4*)p0;
      float4 c = *(const float4*)(p0 + 4);
      float v[8] = {a.x, a.y, a.z, a.w, c.x, c.y, c.z, c.w};
#pragma unroll
      for (int k = 0; k < 8; ++k) {
        _Float16 hi = (_Float16)v[k];
        qh[kk][k] = hi; ql[kk][k] = (_Float16)(v[k] - (float)hi);
      }
    }
  }
  const float gt = gain[h * Tt + tg], bt = bias[h * Tt + tg];

  // E LDS read base: row rS = 32wr + l31, granule 2kk + hi2 (kk via addr XOR kk<<5)
  const int rS = 32 * wr + l31;
  const int eB = rS * 128 + ((hi2 ^ (rS & 7)) << 4);

  // V global-load lane pointers (granule-major tiles; coalesced 16B/lane)
  const int g8a = 4 * wr + hi2;
  const char* vp0 = vtile + g8a * 1024 + l31 * 16;
  const char* vp1 = vtile + g8a * 1024 + (32 + l31) * 16;
  const char* vp2 = vtile + (g8a + 2) * 1024 + l31 * 16;
  const char* vp3 = vtile + (g8a + 2) * 1024 + (32 + l31) * 16;

  f32x16 oacc0 = 0.f, oacc1 = 0.f;   // partial O[t-half wc][d 0..31 / 32..63], this wave's s-half
  float lsum = 0.f;
  f32x16 sA, sB;
  bf16x8 vA[4], vB[4];

  auto STAGE_E = [&](int n, int buf) {
    const char* g = etile + (size_t)n * 16384 + tid * 16;
    char* l = &Eb[buf][0] + tid * 16;
#pragma unroll
    for (int c2 = 0; c2 < 4; ++c2) gll16(g + c2 * 4096, l + c2 * 4096);
  };
  auto SSTEP = [&](int buf, f32x16& acc) {   // S^T = E·Q^T, split f16 (hh + lh + hl)
    const char* ec = &Eb[buf][0];
    acc = 0.f;
#pragma unroll
    for (int kk = 0; kk < 4; ++kk) {
      f16x8 eh = *(const f16x8*)(ec + (eB ^ (kk << 5)));
      f16x8 el = *(const f16x8*)(ec + 8192 + (eB ^ (kk << 5)));
      acc = __builtin_amdgcn_mfma_f32_32x32x16_f16(eh, qh[kk], acc, 0, 0, 0);
      acc = __builtin_amdgcn_mfma_f32_32x32x16_f16(el, qh[kk], acc, 0, 0, 0);
      acc = __builtin_amdgcn_mfma_f32_32x32x16_f16(eh, ql[kk], acc, 0, 0, 0);
    }
  };
  auto VLOAD = [&](int n, bf16x8* vv) {
    const size_t o = (size_t)n * 8192;
    vv[0] = *(const bf16x8*)(vp0 + o);
    vv[1] = *(const bf16x8*)(vp1 + o);
    vv[2] = *(const bf16x8*)(vp2 + o);
    vv[3] = *(const bf16x8*)(vp3 + o);
  };

  // BODY(j): stage E(j+2) [vm order pinned first]; S(j+1) MFMA || LIF(j) VALU (compiler-interleavable);
  //          PV(j); end: s_waitcnt vmcnt(4) [E(j+2) resident, V(j+1) still in flight] + raw barrier.
  auto BODY = [&](int j, f32x16& cur, f32x16& nxt, bf16x8* vc, bf16x8* vn) {
    if (j + 2 <= tb) STAGE_E(j + 2, j & 1);
    __builtin_amdgcn_sched_barrier(0);        // pin vm issue order: E-stage before V-loads
    if (j + 1 <= tb) { SSTEP((j + 1) & 1, nxt); VLOAD(j + 1, vn); }
    // LIF + fixed-shift exp; branchless: arg<0 for non-firing I -> NaN chain -> fmaxf picks e^-62.5
    float p[16];
#pragma unroll
    for (int r = 0; r < 16; ++r) {
      const float I = fmaf(gt, cur[r], bt);
      const float a = (I - 1.0f) * __builtin_fabsf(__builtin_amdgcn_rcpf(I));
      const float L2 = __log2f(a);                                      // NaN unless I > 1
      const float den = fmaf(-0.013862944f, L2, 0.002f);                // tau_ref - tau_rc*ln((I-1)/I)
      const float rd = __builtin_amdgcn_rcpf(den);
      const float pv = __builtin_amdgcn_exp2f(fmaf(0.18033688f, rd, -90.169312f));  // exp(score-62.5)
      p[r] = fmaxf(pv, 7.1892351e-28f);                                 // non-firing: exp(0 - 62.5)
    }
    if (j == tb) {                      // causal mask: only the diagonal tile
#pragma unroll
      for (int rq = 0; rq < 4; ++rq)
#pragma unroll
        for (int rr = 0; rr < 4; ++rr)
          if (32 * wr + 8 * rq + 4 * hi2 + rr > 32 * wc + l31) p[4 * rq + rr] = 0.f;
    }
#pragma unroll
    for (int r = 0; r < 16; ++r) lsum += p[r];
    // PV: pack P to bf16 A-frags in-register (cvt_pk + permlane32_swap), V from registers
#pragma unroll
    for (int kp = 0; kp < 2; ++kp) {
      u32 x0 = cvtpk(p[8 * kp + 0], p[8 * kp + 1]);
      u32 x1 = cvtpk(p[8 * kp + 2], p[8 * kp + 3]);
      u32 y0 = cvtpk(p[8 * kp + 4], p[8 * kp + 5]);
      u32 y1 = cvtpk(p[8 * kp + 6], p[8 * kp + 7]);
      asm("v_permlane32_swap_b32 %0, %1" : "+v"(x0), "+v"(y0));
      asm("v_permlane32_swap_b32 %0, %1" : "+v"(x1), "+v"(y1));
      u32x4 af = {x0, x1, y0, y1};      // lane holds P[t=l31][s_rel = 32wr + 16kp + 8hi2 + 0..7]
      bf16x8 pa = *(bf16x8*)&af;
      oacc0 = __builtin_amdgcn_mfma_f32_32x32x16_bf16(pa, vc[2 * kp + 0], oacc0, 0, 0, 0);
      oacc1 = __builtin_amdgcn_mfma_f32_32x32x16_bf16(pa, vc[2 * kp + 1], oacc1, 0, 0, 0);
    }
  };

  // ---- prologue: E(0),E(1),V(0); S(0) ----
  STAGE_E(0, 0);
  if (tb >= 1) STAGE_E(1, 1);
  __builtin_amdgcn_sched_barrier(0);
  VLOAD(0, vA);
  asm volatile("s_waitcnt vmcnt(4)" ::: "memory");   // E(0),E(1) resident; V(0) in flight
  __builtin_amdgcn_s_barrier();
  __builtin_amdgcn_sched_barrier(0);
  SSTEP(0, sA);
  asm volatile("s_waitcnt vmcnt(4)" ::: "memory");
  __builtin_amdgcn_s_barrier();                      // WAR: Eb[0] reads done before BODY(0) restages it
  __builtin_amdgcn_sched_barrier(0);

  int j = 0;
  for (;;) {
    BODY(j, sA, sB, vA, vB);
    if (j == tb) break;
    asm volatile("s_waitcnt vmcnt(4)" ::: "memory"); // E(j+2) resident; V(j+1) stays in flight
    __builtin_amdgcn_s_barrier();
    __builtin_amdgcn_sched_barrier(0);
    ++j;
    BODY(j, sB, sA, vB, vA);
    if (j == tb) break;
    asm volatile("s_waitcnt vmcnt(4)" ::: "memory");
    __builtin_amdgcn_s_barrier();
    __builtin_amdgcn_sched_barrier(0);
    ++j;
  }

  // ---- epilogue: cross-wave (wr) reduction of O partials + lsum, once per block ----
  lsum += __shfl_xor(lsum, 32);                       // combine hi2 quarters
  if (lane < 32) LsS[wr * 64 + wc * 32 + l31] = lsum; // per-(wr, t) partial over s-half
  __syncthreads();                                    // full drain; Eb safe to reuse below
  float* red = (float*)&Eb[0][0];                     // [wc][t_in_half 0..31][d 0..63] f32
  if (wr == 1) {
#pragma unroll
    for (int rq = 0; rq < 4; ++rq)
#pragma unroll
      for (int rr = 0; rr < 4; ++rr) {
        const int tr = 8 * rq + 4 * hi2 + rr;
        red[wc * 2048 + tr * 64 + l31]      = oacc0[4 * rq + rr];
        red[wc * 2048 + tr * 64 + 32 + l31] = oacc1[4 * rq + rr];
      }
  }
  __syncthreads();
  if (wr == 0) {
    float* ob = out + ((size_t)(b * Hh + h) * Tt + t0 + 32 * wc) * 64;
#pragma unroll
    for (int rq = 0; rq < 4; ++rq) {
      const int tr0 = 8 * rq + 4 * hi2;
      f32x4 lt0 = *(const f32x4*)&LsS[wc * 32 + tr0];        // broadcast reads
      f32x4 lt1 = *(const f32x4*)&LsS[64 + wc * 32 + tr0];
#pragma unroll
      for (int rr = 0; rr < 4; ++rr) {
        const int tr = tr0 + rr;
        const float linv = __builtin_amdgcn_rcpf(lt0[rr] + lt1[rr]);
        const float o0 = oacc0[4 * rq + rr] + red[wc * 2048 + tr * 64 + l31];
        const float o1 = oacc1[4 * rq + rr] + red[wc * 2048 + tr * 64 + 32 + l31];
        ob[(size_t)tr * 64 + l31]      = o0 * linv;
        ob[(size_t)tr * 64 + 32 + l31] = o1 * linv;
      }
    }
  }
}

extern "C" void kernel_launch(void* const* d_in, const int* in_sizes, int n_in,
                              void* d_out, int out_size, void* d_ws, size_t ws_size,
                              hipStream_t stream) {
  const float* Q    = (const float*)d_in[0];
  // d_in[1] = K is UNUSED by the reference (scores use enc_hat)
  const float* V    = (const float*)d_in[2];
  const float* E    = (const float*)d_in[3];
  const float* gain = (const float*)d_in[4];
  const float* bias = (const float*)d_in[5];
  float* out = (float*)d_out;

  constexpr size_t EIMG_BYTES = (size_t)Hh * 32 * 16384;        // 8 MiB
  char* Eimg = (char*)d_ws;
  char* Vimg = (char*)d_ws + EIMG_BYTES;                        // 8 MiB

  prep_e<<<Hh * 32, 256, 0, stream>>>(E, Eimg);
  prep_v<<<Bb * Hh * 32, 256, 0, stream>>>(V, Vimg);
  lif_attn15<<<1024, 256, 0, stream>>>(Q, gain, bias, Eimg, Vimg, out);
}